// Round 1
// baseline (358.536 us; speedup 1.0000x reference)
//
#include <hip/hip_runtime.h>

// PackedAvgPool1d: out[t, :] = mean(x[gather_base[t] + i, :] for i < min(rem[t], K))
// K = 2, S = 2, D = 768. All fp32 (verified: absmax == 0.0).
//
// Memory-bound: 226 MB fp32 read + 113 MB fp32 write = 340 MB -> ~54 us floor
// at 6.3 TB/s achievable. Bench dur_us (~349) folds in two per-iteration
// harness poison fills (944 MB @ ~6.7 TB/s = ~285 us); our dispatch is the
// remaining ~65 us (absent from dur-sorted top-5).
//
// R6: thread-coarsening x2 with stride-kBlock chunk pairing. Each thread
// handles chunks t0 and t0+256 -> both load/store instructions remain fully
// coalesced per-wave, and the thread issues 4 independent x-loads (+ 4
// metadata loads) before any s_waitcnt, doubling memory-level parallelism
// and halving per-byte index/metadata overhead. Exactness preserved:
// cnt==1 clamps the second-row pointer onto the first row so v1 == v0 and
// (v0+v1)*0.5 == v0 exactly; cnt==2: *0.5 == /2 exactly.

namespace {

typedef float vfloat4 __attribute__((ext_vector_type(4)));  // native vec4

constexpr int kD = 768;             // feature dim
constexpr int kVec = 4;             // 4 floats/thread-chunk: 16B load + store
constexpr int kChunks = kD / kVec;  // 192 chunks per row
constexpr int kBlock = 256;
constexpr int kCoarse = 2;                 // chunks per thread
constexpr int kTile = kBlock * kCoarse;    // 512 chunks per block

__device__ __forceinline__ void do_chunk_k2(const float* __restrict__ x,
                                            const int* __restrict__ gbase,
                                            const int* __restrict__ rem,
                                            float* __restrict__ out, int t) {
  const int r = t / kChunks;
  const int c = t - r * kChunks;
  const int base = gbase[r];
  const int cnt = min(rem[r], 2);
  const float* p = x + (size_t)base * kD + (size_t)c * kVec;
  const vfloat4 v0 = *reinterpret_cast<const vfloat4*>(p);
  const vfloat4 v1 = *reinterpret_cast<const vfloat4*>(p + (cnt > 1 ? kD : 0));
  const vfloat4 o = (v0 + v1) * 0.5f;
  __builtin_nontemporal_store(
      o, reinterpret_cast<vfloat4*>(out + (size_t)r * kD + (size_t)c * kVec));
}

__global__ __launch_bounds__(kBlock)
void packed_avgpool1d_kernel(const float* __restrict__ x,
                             const int* __restrict__ gbase,
                             const int* __restrict__ rem,
                             const int* __restrict__ kptr,
                             float* __restrict__ out,
                             int n_chunks_total) {
  const int K = kptr[0];                       // runtime scalar (always 2 here)
  const int t0 = blockIdx.x * kTile + threadIdx.x;
  const int t1 = t0 + kBlock;

  if (K == 2) {                                // wave-uniform; always taken
    if (t1 < n_chunks_total) {
      // Fast path: both chunks valid. Issue all 4 metadata loads, then all
      // 4 x-loads, then both stores — maximum loads-in-flight per thread.
      const int r0 = t0 / kChunks;             // const divide -> magic-mul
      const int c0 = t0 - r0 * kChunks;
      const int r1 = t1 / kChunks;
      const int c1 = t1 - r1 * kChunks;

      const int b0 = gbase[r0];
      const int b1 = gbase[r1];
      const int n0 = min(rem[r0], 2);          // cnt in {1,2}; rem >= 1
      const int n1 = min(rem[r1], 2);

      const float* p0 = x + (size_t)b0 * kD + (size_t)c0 * kVec;
      const float* p1 = x + (size_t)b1 * kD + (size_t)c1 * kVec;

      const vfloat4 a0 = *reinterpret_cast<const vfloat4*>(p0);
      const vfloat4 a1 = *reinterpret_cast<const vfloat4*>(p0 + (n0 > 1 ? kD : 0));
      const vfloat4 b0v = *reinterpret_cast<const vfloat4*>(p1);
      const vfloat4 b1v = *reinterpret_cast<const vfloat4*>(p1 + (n1 > 1 ? kD : 0));

      const vfloat4 o0 = (a0 + a1) * 0.5f;
      const vfloat4 o1 = (b0v + b1v) * 0.5f;

      __builtin_nontemporal_store(
          o0, reinterpret_cast<vfloat4*>(out + (size_t)r0 * kD + (size_t)c0 * kVec));
      __builtin_nontemporal_store(
          o1, reinterpret_cast<vfloat4*>(out + (size_t)r1 * kD + (size_t)c1 * kVec));
    } else {
      // Tail blocks: per-chunk guard.
      #pragma unroll
      for (int u = 0; u < kCoarse; ++u) {
        const int t = t0 + u * kBlock;
        if (t < n_chunks_total) do_chunk_k2(x, gbase, rem, out, t);
      }
    }
  } else {                                     // generic fallback (never hit)
    #pragma unroll
    for (int u = 0; u < kCoarse; ++u) {
      const int t = t0 + u * kBlock;
      if (t >= n_chunks_total) continue;
      const int r = t / kChunks;
      const int c = t - r * kChunks;
      const int base = gbase[r];
      const int cnt = min(rem[r], K);
      const float* p = x + (size_t)base * kD + (size_t)c * kVec;
      vfloat4 acc = {0.0f, 0.0f, 0.0f, 0.0f};
      for (int i = 0; i < cnt; ++i)
        acc += *reinterpret_cast<const vfloat4*>(p + (size_t)i * kD);
      const vfloat4 o = acc * (1.0f / (float)cnt);
      __builtin_nontemporal_store(
          o, reinterpret_cast<vfloat4*>(out + (size_t)r * kD + (size_t)c * kVec));
    }
  }
}

}  // namespace

extern "C" void kernel_launch(void* const* d_in, const int* in_sizes, int n_in,
                              void* d_out, int out_size, void* d_ws, size_t ws_size,
                              hipStream_t stream) {
  const float* x = (const float*)d_in[0];        // [Tx, 768] fp32
  const int* gbase = (const int*)d_in[1];        // [Ty]
  const int* rem = (const int*)d_in[2];          // [Ty]
  const int* kptr = (const int*)d_in[3];         // scalar K
  float* out = (float*)d_out;                    // [Ty, 768] fp32

  const int Ty = in_sizes[1];
  const int total = Ty * kChunks;
  const int blocks = (total + kTile - 1) / kTile;

  hipLaunchKernelGGL(packed_avgpool1d_kernel, dim3(blocks), dim3(kBlock), 0,
                     stream, x, gbase, rem, kptr, out, total);
}

// Round 2
// 349.496 us; speedup vs baseline: 1.0259x; 1.0259x over previous
//
#include <hip/hip_runtime.h>

// PackedAvgPool1d: out[t, :] = mean(x[gather_base[t] + i, :] for i < min(rem[t], K))
// K = 2, S = 2, D = 768. All fp32 (verified: absmax == 0.0).
//
// Memory-bound: 226 MB fp32 read + 113 MB fp32 write = 340 MB -> ~54 us floor
// at 6.3 TB/s achievable copy BW. Bench dur_us (~350) folds in per-iteration
// harness poison fills (944 MB @ ~6.6-6.7 TB/s = ~285 us); our dispatch is
// ~65 us (absent from dur-sorted top-5), i.e. ~5.2 TB/s effective = 83% of
// the m13 copy ceiling on a mixed read+write stream.
//
// R7 = revert to R5 (proven best: 350.2 / 349.5 us across two sessions).
// R6 post-mortem: x2 thread-coarsening (stride-kBlock pairing, 4 loads in
// flight/thread) regressed to 358.5 us. The kernel is NOT MLP-limited: at
// 8-VGPR full occupancy the device already has enough waves x 2 loads each
// to saturate the HBM controllers; coarsening added nothing to the memory
// stream. Metadata loads are L1-broadcast and free. Remaining gap to the
// copy ceiling (~3% of headline) is within cross-container bench noise.
//
// Exactness: rem >= 1 always; cnt == 1 clamps the second-row pointer onto
// the first row so v1 == v0 and (v0 + v1) * 0.5 == v0 EXACTLY; cnt == 2:
// * 0.5 == / 2 exactly. Nontemporal store: out is stream-once; keep L2
// for x and metadata.

namespace {

typedef float vfloat4 __attribute__((ext_vector_type(4)));  // native vec4

constexpr int kD = 768;             // feature dim
constexpr int kVec = 4;             // 4 floats/thread: 16B load + 16B store
constexpr int kChunks = kD / kVec;  // 192 chunks per row
constexpr int kBlock = 256;

__global__ __launch_bounds__(kBlock)
void packed_avgpool1d_kernel(const float* __restrict__ x,
                             const int* __restrict__ gbase,
                             const int* __restrict__ rem,
                             const int* __restrict__ kptr,
                             float* __restrict__ out,
                             int n_chunks_total) {
  const int t = blockIdx.x * kBlock + threadIdx.x;
  if (t >= n_chunks_total) return;

  const int K = kptr[0];                 // runtime scalar (always 2 here)
  const int row = t / kChunks;           // const divide -> magic-mul
  const int c = t - row * kChunks;

  const int base = gbase[row];
  const int cnt = min(rem[row], K);      // cnt in {1, 2}; rem >= 1 guaranteed

  const float* p = x + (size_t)base * kD + (size_t)c * kVec;
  float* po = out + (size_t)row * kD + (size_t)c * kVec;

  if (K == 2) {                          // wave-uniform; always taken here
    // Clamp second-row ptr into row 0 when cnt==1 -> always in-bounds, and
    // v1 == v0 makes the averaging formula exact for both cnt values.
    const float* p1 = p + (cnt > 1 ? kD : 0);
    const vfloat4 v0 = *reinterpret_cast<const vfloat4*>(p);
    const vfloat4 v1 = *reinterpret_cast<const vfloat4*>(p1);
    const vfloat4 o = (v0 + v1) * 0.5f;
    __builtin_nontemporal_store(o, reinterpret_cast<vfloat4*>(po));
  } else {                               // generic fallback (never hit: K==2)
    vfloat4 acc = {0.0f, 0.0f, 0.0f, 0.0f};
    for (int i = 0; i < cnt; ++i)
      acc += *reinterpret_cast<const vfloat4*>(p + (size_t)i * kD);
    const vfloat4 o = acc * (1.0f / (float)cnt);
    __builtin_nontemporal_store(o, reinterpret_cast<vfloat4*>(po));
  }
}

}  // namespace

extern "C" void kernel_launch(void* const* d_in, const int* in_sizes, int n_in,
                              void* d_out, int out_size, void* d_ws, size_t ws_size,
                              hipStream_t stream) {
  const float* x = (const float*)d_in[0];        // [Tx, 768] fp32
  const int* gbase = (const int*)d_in[1];        // [Ty]
  const int* rem = (const int*)d_in[2];          // [Ty]
  const int* kptr = (const int*)d_in[3];         // scalar K
  float* out = (float*)d_out;                    // [Ty, 768] fp32

  const int Ty = in_sizes[1];
  const int total = Ty * kChunks;
  const int blocks = (total + kBlock - 1) / kBlock;

  hipLaunchKernelGGL(packed_avgpool1d_kernel, dim3(blocks), dim3(kBlock), 0,
                     stream, x, gbase, rem, kptr, out, total);
}